// Round 3
// baseline (377.939 us; speedup 1.0000x reference)
//
#include <hip/hip_runtime.h>

typedef __bf16 bf16x8 __attribute__((ext_vector_type(8)));
typedef float  f32x4  __attribute__((ext_vector_type(4)));
typedef unsigned u32x4 __attribute__((ext_vector_type(4)));

__device__ __forceinline__ unsigned short f2bf(float f) {
  unsigned u = __float_as_uint(f);
  u += 0x7FFFu + ((u >> 16) & 1u);   // round-to-nearest-even
  return (unsigned short)(u >> 16);
}

#define WF_BYTES 147456  // 9 taps * 2 ci-chunks * 8 cout-blocks * 64 lanes * 16 B

// ---- weight transform: W[128][64][3][3] f32 -> bf16 MFMA B-fragment layout
// wf[(((kh*3+kw)*2+ck)*8+nb)*64 + lane][j] = W[nb*16+(lane&15)][ck*32+(lane>>4)*8+j][kh][kw]
__global__ __launch_bounds__(64) void wxf_746(const float* __restrict__ w,
                                              unsigned short* __restrict__ wf) {
  const int b = blockIdx.x;            // 0..143
  const int lane = threadIdx.x;        // 0..63
  const int nb = b & 7, ck = (b >> 3) & 1, pos = b >> 4;
  const int kh = pos / 3, kw = pos % 3;
  const int co = nb * 16 + (lane & 15);
  const int ci0 = ck * 32 + ((lane >> 4) << 3);
  unsigned short* o = wf + ((size_t)(b * 64 + lane) << 3);
#pragma unroll
  for (int j = 0; j < 8; ++j)
    o[j] = f2bf(w[((co * 64 + ci0 + j) * 3 + kh) * 3 + kw]);
}

// ---- fused conv3x3 + bias + relu + maxpool2x2, implicit GEMM, bf16 MFMA
// 1 WG (256 thr, 4 waves) = (n, pooled row hpair). Conv rows h0,h0+1 x 128 cout.
// Waves: wr = wid>>1 (conv row), wh = wid&1 (64-cout half), nf=4 -> acc[7][4], A-reuse x4.
// K(ci) split in two staged phases ck=0,1 -> LDS tile only 29.2 KB -> 4 WGs/CU.
// LDS x tile: [4 rows][114 cols][32 ci] bf16; byte = r*7296 + col*64 + ((ci2) ^ (((col>>1)&3)<<4))
__global__ __launch_bounds__(256, 4) void conv_746(
    const float* __restrict__ x, const unsigned char* __restrict__ wsb,
    const float* __restrict__ bias, float* __restrict__ out) {
  __shared__ __align__(16) unsigned char lds[29184];
  const int bx = blockIdx.x;
  const int n = bx / 56, hpair = bx % 56, h0 = hpair * 2;
  const int tid = threadIdx.x;
  const int lane = tid & 63, wid = tid >> 6;
  const int wr = wid >> 1, wh = wid & 1;      // wave conv-row (0/1), wave cout-half (0/1)
  const int lw = lane & 15, hq = lane >> 4;

  float bb[4];
#pragma unroll
  for (int nf = 0; nf < 4; ++nf) bb[nf] = bias[(wh * 4 + nf) * 16 + lw];

  const f32x4 z4 = {0.f, 0.f, 0.f, 0.f};
  // zero pad columns 0 (w=-1) and 113 (w=112), all 4 rows (persist across both ck phases)
  if (tid < 32) {
    const int r = tid >> 3, csel = (tid >> 2) & 1, s = tid & 3;
    const int col = csel ? 113 : 0;
    *(f32x4*)&lds[r * 7296 + col * 64 + s * 16] = z4;
  }

  const int scol = tid & 127;      // w coord (112..127 idle)
  const int cig8 = tid >> 7;       // 16-ci group within the 32-ci phase
  const float* xn = x + (size_t)n * 802816;

  f32x4 acc[7][4];
#pragma unroll
  for (int f = 0; f < 7; ++f)
#pragma unroll
    for (int nf = 0; nf < 4; ++nf) acc[f][nf] = z4;

#pragma unroll
  for (int ck = 0; ck < 2; ++ck) {
    // ---- stage phase ck: rows h0-1..h0+2, ci = ck*32..ck*32+31, fp32 -> bf16
#pragma unroll
    for (int r = 0; r < 4; ++r) {
      const int h = h0 - 1 + r;
      if (h < 0 || h >= 112) {
        if (ck == 0) {   // zero once; stage(1) never touches invalid rows
          for (int off = tid * 16; off < 7296; off += 4096)
            *(f32x4*)&lds[r * 7296 + off] = z4;
        }
      } else if (scol < 112) {
        const int col = scol + 1;
        const int sw = ((col >> 1) & 3) << 4;
        const int cb = r * 7296 + col * 64;
        const float* xr = xn + (size_t)h * 112 + scol;
#pragma unroll
        for (int half = 0; half < 2; ++half) {
          const int ci0 = ck * 32 + cig8 * 16 + half * 8;
          unsigned pk[4];
#pragma unroll
          for (int m = 0; m < 4; ++m) {
            const float f0 = xr[(size_t)(ci0 + 2 * m) * 12544];
            const float f1 = xr[(size_t)(ci0 + 2 * m + 1) * 12544];
            pk[m] = (unsigned)f2bf(f0) | ((unsigned)f2bf(f1) << 16);
          }
          *(u32x4*)&lds[cb + ((cig8 * 32 + half * 16) ^ sw)] = *(u32x4*)pk;
        }
      }
    }
    __syncthreads();

    // ---- compute phase ck: 9 taps x 7 f, nf=4
#pragma unroll
    for (int kh = 0; kh < 3; ++kh) {
#pragma unroll
      for (int kw = 0; kw < 3; ++kw) {
        const int col0 = lw + kw;
        const int sw = ((col0 >> 1) & 3) << 4;
        const int abase = (wr + kh) * 7296 + col0 * 64 + ((hq * 16) ^ sw);
        const unsigned char* bp =
            wsb + (((size_t)(((kh * 3 + kw) * 2 + ck) * 8 + wh * 4) * 64 + lane) << 4);
        bf16x8 bfr[4];
#pragma unroll
        for (int nf = 0; nf < 4; ++nf)
          bfr[nf] = *(const bf16x8*)(bp + (nf << 10));
#pragma unroll
        for (int f = 0; f < 7; ++f) {
          const bf16x8 a = *(const bf16x8*)&lds[abase + f * 1024];
#pragma unroll
          for (int nf = 0; nf < 4; ++nf)
            acc[f][nf] = __builtin_amdgcn_mfma_f32_16x16x32_bf16(a, bfr[nf], acc[f][nf], 0, 0, 0);
        }
      }
    }
    __syncthreads();   // protects LDS tile before restage (ck=0) / epilogue reuse (ck=1)
  }

  // bias + relu + horizontal pool (in-lane: acc regs are 4 consecutive w)
  float pl0[7][4], pl1[7][4];
#pragma unroll
  for (int f = 0; f < 7; ++f)
#pragma unroll
    for (int nf = 0; nf < 4; ++nf) {
      const float a0 = fmaxf(acc[f][nf][0] + bb[nf], 0.f);
      const float a1 = fmaxf(acc[f][nf][1] + bb[nf], 0.f);
      const float a2 = fmaxf(acc[f][nf][2] + bb[nf], 0.f);
      const float a3 = fmaxf(acc[f][nf][3] + bb[nf], 0.f);
      pl0[f][nf] = fmaxf(a0, a1);
      pl1[f][nf] = fmaxf(a2, a3);
    }
  float* pb = (float*)lds;    // [128 co][56 pw] f32 = 28672 B
  if (wr == 0) {
#pragma unroll
    for (int f = 0; f < 7; ++f)
#pragma unroll
      for (int nf = 0; nf < 4; ++nf) {
        const int co = (wh * 4 + nf) * 16 + lw;
        const int pw = f * 8 + hq * 2;
        pb[co * 56 + pw] = pl0[f][nf];
        pb[co * 56 + pw + 1] = pl1[f][nf];
      }
  }
  __syncthreads();
  if (wr == 1) {   // vertical pool: combine with row-0 partials, write back
#pragma unroll
    for (int f = 0; f < 7; ++f)
#pragma unroll
      for (int nf = 0; nf < 4; ++nf) {
        const int co = (wh * 4 + nf) * 16 + lw;
        const int pw = f * 8 + hq * 2;
        pb[co * 56 + pw] = fmaxf(pl0[f][nf], pb[co * 56 + pw]);
        pb[co * 56 + pw + 1] = fmaxf(pl1[f][nf], pb[co * 56 + pw + 1]);
      }
  }
  __syncthreads();
  // cooperative coalesced output: [128 co][56 pw] -> out[n][co][hpair][:]
  const float* pbc = (const float*)lds;
#pragma unroll
  for (int i = 0; i < 7; ++i) {
    const int idx = i * 256 + tid;            // 0..1791 float4s
    const int co = idx / 14, q = idx - co * 14;
    const f32x4 v = *(const f32x4*)&pbc[co * 56 + q * 4];
    *(f32x4*)(out + (size_t)(n * 128 + co) * 3136 + hpair * 56 + q * 4) = v;
  }
}

// ---- safety fallback if workspace is too small (should never trigger)
__global__ __launch_bounds__(256) void naive_746(
    const float* __restrict__ x, const float* __restrict__ wt,
    const float* __restrict__ bias, float* __restrict__ out) {
  int idx = blockIdx.x * 256 + threadIdx.x;
  if (idx >= 12845056) return;
  int pw = idx % 56; int t = idx / 56;
  int ph = t % 56; t /= 56;
  int co = t % 128; int n = t / 128;
  float best = 0.f;  // relu output >= 0
  for (int dh = 0; dh < 2; ++dh)
    for (int dw = 0; dw < 2; ++dw) {
      int oh = ph * 2 + dh, ow = pw * 2 + dw;
      float acc = bias[co];
      for (int ci = 0; ci < 64; ++ci) {
        const float* xp = x + ((size_t)(n * 64 + ci) * 112) * 112;
        const float* wp = wt + (co * 64 + ci) * 9;
        for (int kh = 0; kh < 3; ++kh) {
          int ih = oh + kh - 1; if (ih < 0 || ih >= 112) continue;
          for (int kw = 0; kw < 3; ++kw) {
            int iw = ow + kw - 1; if (iw < 0 || iw >= 112) continue;
            acc += xp[ih * 112 + iw] * wp[kh * 3 + kw];
          }
        }
      }
      best = fmaxf(best, fmaxf(acc, 0.f));
    }
  out[idx] = best;
}

extern "C" void kernel_launch(void* const* d_in, const int* in_sizes, int n_in,
                              void* d_out, int out_size, void* d_ws, size_t ws_size,
                              hipStream_t stream) {
  const float* x = (const float*)d_in[0];
  const float* w = (const float*)d_in[1];
  const float* b = (const float*)d_in[2];
  float* o = (float*)d_out;
  if (ws_size < (size_t)WF_BYTES) {
    naive_746<<<dim3((12845056 + 255) / 256), dim3(256), 0, stream>>>(x, w, b, o);
    return;
  }
  unsigned short* wf = (unsigned short*)d_ws;
  wxf_746<<<dim3(144), dim3(64), 0, stream>>>(w, wf);
  conv_746<<<dim3(1792), dim3(256), 0, stream>>>(x, (const unsigned char*)d_ws, b, o);
}

// Round 4
// 91.826 us; speedup vs baseline: 4.1158x; 4.1158x over previous
//
#include <hip/hip_runtime.h>

typedef __bf16 bf16x8 __attribute__((ext_vector_type(8)));
typedef float  f32x4  __attribute__((ext_vector_type(4)));

__device__ __forceinline__ unsigned short f2bf(float f) {
  unsigned u = __float_as_uint(f);
  u += 0x7FFFu + ((u >> 16) & 1u);   // round-to-nearest-even
  return (unsigned short)(u >> 16);
}

__device__ __forceinline__ unsigned cvtpk(float lo, float hi) {
  unsigned r;
  asm("v_cvt_pk_bf16_f32 %0, %1, %2" : "=v"(r) : "v"(lo), "v"(hi));
  return r;
}

#define WF_BYTES 147456  // 9 taps * 2 ci-chunks * 8 cout-blocks * 64 lanes * 16 B

// ---- weight transform: W[128][64][3][3] f32 -> bf16 MFMA B-fragment layout
// wf[(((kh*3+kw)*2+ck)*8+nb)*64 + lane][j] = W[nb*16+(lane&15)][ck*32+(lane>>4)*8+j][kh][kw]
__global__ __launch_bounds__(64) void wxf_746(const float* __restrict__ w,
                                              unsigned short* __restrict__ wf) {
  const int b = blockIdx.x;            // 0..143
  const int lane = threadIdx.x;        // 0..63
  const int nb = b & 7, ck = (b >> 3) & 1, pos = b >> 4;
  const int kh = pos / 3, kw = pos % 3;
  const int co = nb * 16 + (lane & 15);
  const int ci0 = ck * 32 + ((lane >> 4) << 3);
  unsigned short* o = wf + ((size_t)(b * 64 + lane) << 3);
#pragma unroll
  for (int j = 0; j < 8; ++j)
    o[j] = f2bf(w[((co * 64 + ci0 + j) * 3 + kh) * 3 + kw]);
}

// ---- fused conv3x3 + bias + relu + maxpool2x2, implicit GEMM, bf16 MFMA
// 1 WG (256 thr, 4 waves) = (n, pooled row hpair). Conv rows h0,h0+1 x 128 cout.
// Waves: wr = wid>>1 (conv row), wh = wid&1 (64-cout half), nf=4 -> acc[7][4].
// ci split in two 32-ci phases, DOUBLE-BUFFERED: stage(ck1) overlaps compute(ck0).
// VGPR cap 256 (launch_bounds min-waves 2): acc stays resident, no spills; LDS caps
// occupancy at 2 WGs/CU anyway (2 x 29184 B buffers).
// LDS x tile per buf: [4 rows][114 cols][32 ci] bf16
//   byte = r*7296 + col*64 + ((chunk ^ ((col>>2)&3))<<4) + within-chunk, chunk = ci/8
__global__ __launch_bounds__(256, 2) void conv_746(
    const float* __restrict__ x, const unsigned char* __restrict__ wsb,
    const float* __restrict__ bias, float* __restrict__ out) {
  __shared__ __align__(16) unsigned char lds[58368];
  const int bx = blockIdx.x;
  const int n = bx / 56, hpair = bx % 56, h0 = hpair * 2;
  const int tid = threadIdx.x;
  const int lane = tid & 63, wid = tid >> 6;
  const int wr = wid >> 1, wh = wid & 1;      // wave conv-row (0/1), wave cout-half (0/1)
  const int lw = lane & 15, hq = lane >> 4;

  float bb[4];
#pragma unroll
  for (int nf = 0; nf < 4; ++nf) bb[nf] = bias[(wh * 4 + nf) * 16 + lw];

  const f32x4 z4 = {0.f, 0.f, 0.f, 0.f};
  // zero pad columns 0 (w=-1) and 113 (w=112), 4 rows, BOTH buffers
  if (tid < 64) {
    const int bufi = tid & 1, colsel = (tid >> 1) & 1;
    const int r = (tid >> 2) & 3, s = tid >> 4;
    const int col = colsel ? 113 : 0;
    *(f32x4*)&lds[bufi * 29184 + r * 7296 + col * 64 + s * 16] = z4;
  }
  // out-of-image rows -> zeros (persist; stage never writes them)
  if (hpair == 0) {
    for (int i = tid; i < 912; i += 256) {
      const int bufi = i >= 456;
      *(f32x4*)&lds[bufi * 29184 + /*r=0*/ (i - bufi * 456) * 16] = z4;
    }
  }
  if (hpair == 55) {
    for (int i = tid; i < 912; i += 256) {
      const int bufi = i >= 456;
      *(f32x4*)&lds[bufi * 29184 + 3 * 7296 + (i - bufi * 456) * 16] = z4;
    }
  }

  const float* xn = x + (size_t)n * 802816;

  // stage phase ck into buf: w-major float4 loads (coalesced), cvt_pk, swizzled b32 writes
  auto stage = [&](int ck, unsigned char* buf) {
#pragma unroll
    for (int i = 0; i < 7; ++i) {
      const int idx = i * 256 + tid;          // 1792 quads = 28 w4 x 16 cg x 4 r
      const int w4 = idx % 28;
      const int cg = (idx / 28) & 15;         // ci-pair index within 32-ci phase
      const int r = idx / 448;
      const int h = h0 - 1 + r;
      if (h >= 0 && h < 112) {
        const float* xp = xn + (size_t)(ck * 32 + cg * 2) * 12544 + h * 112 + w4 * 4;
        const f32x4 a0 = *(const f32x4*)xp;
        const f32x4 a1 = *(const f32x4*)(xp + 12544);
        const int rb = r * 7296 + (cg & 3) * 4;
        const int ch = cg >> 2;
#pragma unroll
        for (int q = 0; q < 4; ++q) {
          const int col = w4 * 4 + q + 1;
          const unsigned pk = cvtpk(a0[q], a1[q]);
          *(unsigned*)&buf[rb + col * 64 + ((ch ^ ((col >> 2) & 3)) << 4)] = pk;
        }
      }
    }
  };

  f32x4 acc[7][4];
#pragma unroll
  for (int f = 0; f < 7; ++f)
#pragma unroll
    for (int nf = 0; nf < 4; ++nf) acc[f][nf] = z4;

  auto compute = [&](int ck, const unsigned char* buf) {
#pragma unroll
    for (int kh = 0; kh < 3; ++kh) {
#pragma unroll
      for (int kw = 0; kw < 3; ++kw) {
        const int c0 = lw + kw;               // col = f*16 + c0; swizzle f-invariant
        const int abase = (wr + kh) * 7296 + c0 * 64 + ((hq ^ ((c0 >> 2) & 3)) << 4);
        const unsigned char* bp =
            wsb + (((size_t)(((kh * 3 + kw) * 2 + ck) * 8 + wh * 4) * 64 + lane) << 4);
        bf16x8 bfr[4];
#pragma unroll
        for (int nf = 0; nf < 4; ++nf)
          bfr[nf] = *(const bf16x8*)(bp + (nf << 10));
#pragma unroll
        for (int f = 0; f < 7; ++f) {
          const bf16x8 a = *(const bf16x8*)&buf[abase + f * 1024];
#pragma unroll
          for (int nf = 0; nf < 4; ++nf)
            acc[f][nf] = __builtin_amdgcn_mfma_f32_16x16x32_bf16(a, bfr[nf], acc[f][nf], 0, 0, 0);
        }
      }
    }
  };

  stage(0, lds);
  __syncthreads();              // buf0 ready
  stage(1, lds + 29184);        // overlaps compute(0): independent buffer
  compute(0, lds);
  __syncthreads();              // buf1 ready (and all buf0 reads done)
  compute(1, lds + 29184);

  // bias + relu + horizontal pool (in-lane: acc regs are 4 consecutive w)
  float pl0[7][4], pl1[7][4];
#pragma unroll
  for (int f = 0; f < 7; ++f)
#pragma unroll
    for (int nf = 0; nf < 4; ++nf) {
      const float a0 = fmaxf(acc[f][nf][0] + bb[nf], 0.f);
      const float a1 = fmaxf(acc[f][nf][1] + bb[nf], 0.f);
      const float a2 = fmaxf(acc[f][nf][2] + bb[nf], 0.f);
      const float a3 = fmaxf(acc[f][nf][3] + bb[nf], 0.f);
      pl0[f][nf] = fmaxf(a0, a1);
      pl1[f][nf] = fmaxf(a2, a3);
    }
  float* pb = (float*)lds;    // [128 co][56 pw] f32 = 28672 B (buf0 region, reads done)
  if (wr == 0) {
#pragma unroll
    for (int f = 0; f < 7; ++f)
#pragma unroll
      for (int nf = 0; nf < 4; ++nf) {
        const int co = (wh * 4 + nf) * 16 + lw;
        const int pw = f * 8 + hq * 2;
        pb[co * 56 + pw] = pl0[f][nf];
        pb[co * 56 + pw + 1] = pl1[f][nf];
      }
  }
  __syncthreads();
  if (wr == 1) {   // vertical pool: combine with row-0 partials
#pragma unroll
    for (int f = 0; f < 7; ++f)
#pragma unroll
      for (int nf = 0; nf < 4; ++nf) {
        const int co = (wh * 4 + nf) * 16 + lw;
        const int pw = f * 8 + hq * 2;
        pb[co * 56 + pw] = fmaxf(pl0[f][nf], pb[co * 56 + pw]);
        pb[co * 56 + pw + 1] = fmaxf(pl1[f][nf], pb[co * 56 + pw + 1]);
      }
  }
  __syncthreads();
  // cooperative coalesced output: [128 co][56 pw] -> out[n][co][hpair][:]
  const float* pbc = (const float*)lds;
#pragma unroll
  for (int i = 0; i < 7; ++i) {
    const int idx = i * 256 + tid;            // 0..1791 float4s
    const int co = idx / 14, q = idx - co * 14;
    const f32x4 v = *(const f32x4*)&pbc[co * 56 + q * 4];
    *(f32x4*)(out + (size_t)(n * 128 + co) * 3136 + hpair * 56 + q * 4) = v;
  }
}

// ---- safety fallback if workspace is too small (should never trigger)
__global__ __launch_bounds__(256) void naive_746(
    const float* __restrict__ x, const float* __restrict__ wt,
    const float* __restrict__ bias, float* __restrict__ out) {
  int idx = blockIdx.x * 256 + threadIdx.x;
  if (idx >= 12845056) return;
  int pw = idx % 56; int t = idx / 56;
  int ph = t % 56; t /= 56;
  int co = t % 128; int n = t / 128;
  float best = 0.f;  // relu output >= 0
  for (int dh = 0; dh < 2; ++dh)
    for (int dw = 0; dw < 2; ++dw) {
      int oh = ph * 2 + dh, ow = pw * 2 + dw;
      float acc = bias[co];
      for (int ci = 0; ci < 64; ++ci) {
        const float* xp = x + ((size_t)(n * 64 + ci) * 112) * 112;
        const float* wp = wt + (co * 64 + ci) * 9;
        for (int kh = 0; kh < 3; ++kh) {
          int ih = oh + kh - 1; if (ih < 0 || ih >= 112) continue;
          for (int kw = 0; kw < 3; ++kw) {
            int iw = ow + kw - 1; if (iw < 0 || iw >= 112) continue;
            acc += xp[ih * 112 + iw] * wp[kh * 3 + kw];
          }
        }
      }
      best = fmaxf(best, fmaxf(acc, 0.f));
    }
  out[idx] = best;
}

extern "C" void kernel_launch(void* const* d_in, const int* in_sizes, int n_in,
                              void* d_out, int out_size, void* d_ws, size_t ws_size,
                              hipStream_t stream) {
  const float* x = (const float*)d_in[0];
  const float* w = (const float*)d_in[1];
  const float* b = (const float*)d_in[2];
  float* o = (float*)d_out;
  if (ws_size < (size_t)WF_BYTES) {
    naive_746<<<dim3((12845056 + 255) / 256), dim3(256), 0, stream>>>(x, w, b, o);
    return;
  }
  unsigned short* wf = (unsigned short*)d_ws;
  wxf_746<<<dim3(144), dim3(64), 0, stream>>>(w, wf);
  conv_746<<<dim3(1792), dim3(256), 0, stream>>>(x, (const unsigned char*)d_ws, b, o);
}